// Round 6
// baseline (1279.540 us; speedup 1.0000x reference)
//
#include <hip/hip_runtime.h>

#define T_DIM 4096
#define K1    4096      // H (hidden)
#define I_DIM 11008
#define QMAXF 127.0f

typedef int v4i  __attribute__((ext_vector_type(4)));
typedef int v16i __attribute__((ext_vector_type(16)));

// ---------------- helpers ----------------

__device__ __forceinline__ void gload16(const void* g, void* l) {
  __builtin_amdgcn_global_load_lds((__attribute__((address_space(1))) unsigned int*)(g),
                                   (__attribute__((address_space(3))) unsigned int*)(l),
                                   16, 0, 0);
}

__device__ __forceinline__ int packq(float a, float b, float c, float d) {
  return ((int)a & 255) | (((int)b & 255) << 8) | (((int)c & 255) << 16) | (((int)d & 255) << 24);
}

#define MFMA32(A, B, C) __builtin_amdgcn_mfma_i32_32x32x32_i8(A, B, C, 0, 0, 0)

// ---------------- pass 1: absmax(x) ----------------

__global__ void absmax_x_kernel(const float4* __restrict__ x4, unsigned* __restrict__ maxbits, int n4) {
  int tid = blockIdx.x * blockDim.x + threadIdx.x;
  int stride = gridDim.x * blockDim.x;
  float m = 0.f;
  for (int i = tid; i < n4; i += stride) {
    float4 v = x4[i];
    m = fmaxf(m, fmaxf(fmaxf(fabsf(v.x), fabsf(v.y)), fmaxf(fabsf(v.z), fabsf(v.w))));
  }
  #pragma unroll
  for (int off = 32; off; off >>= 1) m = fmaxf(m, __shfl_xor(m, off));
  if ((threadIdx.x & 63) == 0) atomicMax(maxbits, __float_as_uint(m));
}

// ---------------- pass 2: quantize x ----------------

__global__ void quant_x_kernel(const float4* __restrict__ x4, v4i* __restrict__ q4,
                               const unsigned* __restrict__ scal) {
  const float sx = __uint_as_float(scal[0]) * (1.0f / QMAXF);
  const long i = (long)blockIdx.x * blockDim.x + threadIdx.x;  // 16 floats per thread
  v4i o;
  #pragma unroll
  for (int j = 0; j < 4; ++j) {
    float4 v = x4[i * 4 + j];
    float a = fminf(fmaxf(rintf(v.x / sx), -QMAXF), QMAXF);
    float b = fminf(fmaxf(rintf(v.y / sx), -QMAXF), QMAXF);
    float c = fminf(fmaxf(rintf(v.z / sx), -QMAXF), QMAXF);
    float d = fminf(fmaxf(rintf(v.w / sx), -QMAXF), QMAXF);
    o[j] = packq(a, b, c, d);
  }
  q4[i] = o;
}

// ---------------- weight f32(int-valued) -> int8 ----------------

__global__ void conv_w_kernel(const float4* __restrict__ w4, v4i* __restrict__ q4) {
  const long i = (long)blockIdx.x * blockDim.x + threadIdx.x;  // 16 floats per thread
  v4i o;
  #pragma unroll
  for (int j = 0; j < 4; ++j) {
    float4 v = w4[i * 4 + j];
    o[j] = packq(rintf(v.x), rintf(v.y), rintf(v.z), rintf(v.w));
  }
  q4[i] = o;
}

// ---------------- GEMM1 fused: int8 GEMM + dequant + silu*mul + h absmax ----------------
// 256x256 tile (256 T-rows x 256 staged B-rows = 128 fused h-cols), BK=64.
// 512 thr = 8 waves (4M x 2N), per-wave 64 rows x 128 staged cols, acc[2][4] v16i.
// LDS: 4-buffer ring (128 KB), tile layout [kslot:4][row:256][16B], distance-3 prefetch.
// ONE sync point per tile: {vmcnt(counted) -> s_barrier -> clobber}. Body = 4 gloads +
// 12 ds_reads + 16 MFMA, compiler-scheduled (partial lgkmcnt emitted by hipcc).
// 4-tile unroll makes ring indices compile-time constants.

#define TILE_BODY(U, W, S, ACCSTMTS)                                        \
  {                                                                         \
    asm volatile("s_waitcnt vmcnt(" #W ")" ::: "memory");                   \
    __builtin_amdgcn_s_barrier();                                           \
    asm volatile("" ::: "memory");                                          \
    if (S) {                                                                \
      gload16(gAs + (U) * 64,      &L[((U) + 3) & 3][lA]);                  \
      gload16(gAs + (U) * 64 + 32, &L[((U) + 3) & 3][lA + 8192]);           \
      gload16(gBs + (U) * 64,      &L[((U) + 3) & 3][lB]);                  \
      gload16(gBs + (U) * 64 + 32, &L[((U) + 3) & 3][lB + 8192]);           \
    }                                                                       \
    const signed char* Lb = L[(U)];                                         \
    v4i a0 = *(const v4i*)&Lb[kgl * 4096 + ab];                             \
    v4i a1 = *(const v4i*)&Lb[kgl * 4096 + ab + 512];                       \
    v4i b0 = *(const v4i*)&Lb[kgl * 4096 + bb];                             \
    v4i b1 = *(const v4i*)&Lb[kgl * 4096 + bb + 512];                       \
    v4i b2 = *(const v4i*)&Lb[kgl * 4096 + bb + 1024];                      \
    v4i b3 = *(const v4i*)&Lb[kgl * 4096 + bb + 1536];                      \
    v4i a2 = *(const v4i*)&Lb[(2 + kgl) * 4096 + ab];                       \
    v4i a3 = *(const v4i*)&Lb[(2 + kgl) * 4096 + ab + 512];                 \
    v4i b4 = *(const v4i*)&Lb[(2 + kgl) * 4096 + bb];                       \
    v4i b5 = *(const v4i*)&Lb[(2 + kgl) * 4096 + bb + 512];                 \
    v4i b6 = *(const v4i*)&Lb[(2 + kgl) * 4096 + bb + 1024];                \
    v4i b7 = *(const v4i*)&Lb[(2 + kgl) * 4096 + bb + 1536];                \
    ACCSTMTS                                                                \
  }

#define ACC_16(acc)                                                         \
    acc[0][0] = MFMA32(a0, b0, acc[0][0]);                                  \
    acc[0][1] = MFMA32(a0, b1, acc[0][1]);                                  \
    acc[0][2] = MFMA32(a0, b2, acc[0][2]);                                  \
    acc[0][3] = MFMA32(a0, b3, acc[0][3]);                                  \
    acc[1][0] = MFMA32(a1, b0, acc[1][0]);                                  \
    acc[1][1] = MFMA32(a1, b1, acc[1][1]);                                  \
    acc[1][2] = MFMA32(a1, b2, acc[1][2]);                                  \
    acc[1][3] = MFMA32(a1, b3, acc[1][3]);                                  \
    acc[0][0] = MFMA32(a2, b4, acc[0][0]);                                  \
    acc[0][1] = MFMA32(a2, b5, acc[0][1]);                                  \
    acc[0][2] = MFMA32(a2, b6, acc[0][2]);                                  \
    acc[0][3] = MFMA32(a2, b7, acc[0][3]);                                  \
    acc[1][0] = MFMA32(a3, b4, acc[1][0]);                                  \
    acc[1][1] = MFMA32(a3, b5, acc[1][1]);                                  \
    acc[1][2] = MFMA32(a3, b6, acc[1][2]);                                  \
    acc[1][3] = MFMA32(a3, b7, acc[1][3]);

__global__ __launch_bounds__(512, 2)
void gemm1_silu_kernel(const signed char* __restrict__ qx,
                       const signed char* __restrict__ w8,
                       const float* __restrict__ sgu,
                       unsigned* __restrict__ scal,
                       float* __restrict__ hbuf)
{
  __shared__ signed char L[4][32768];   // per buf: A [0,16384), B [16384,32768)

  const int tid  = threadIdx.x;
  const int lane = tid & 63;
  const int wid  = tid >> 6;       // 0..7
  const int wr   = wid >> 1;       // 0..3  (64-row band)
  const int wc   = wid & 1;        // 0..1  (128 staged-B rows)
  const int l31  = lane & 31;
  const int kgl  = lane >> 5;

  const int lin = blockIdx.x;                  // 1376 = 8*172
  const int sw  = (lin & 7) * 172 + (lin >> 3);
  const int brow = (sw & 15) * 256;
  const int bcol = (sw >> 4) * 128;            // h-col base

  const int sr = tid & 255, sk = tid >> 8;
  const signed char* gA = qx + (size_t)(brow + sr) * K1 + sk * 16;
  const int grp = sr >> 6, w = sr & 63;
  const int gcolw = bcol + grp * 32 + (w & 31);
  const size_t srcrow = (w < 32) ? (size_t)gcolw : (size_t)(I_DIM + gcolw);
  const signed char* gB = w8 + srcrow * K1 + sk * 16;
  const int lA = tid * 16;
  const int lB = 16384 + tid * 16;

  const int ab = (wr * 64 + l31) * 16;
  const int bb = 16384 + (wc * 128 + l31) * 16;

  v16i zero = {0};
  v16i acc[2][4];
  #pragma unroll
  for (int m = 0; m < 2; ++m)
    #pragma unroll
    for (int n = 0; n < 4; ++n) acc[m][n] = zero;

  const int nk = K1 / 64;  // 64
  #pragma unroll
  for (int t = 0; t < 3; ++t) {
    gload16(gA + t * 64,      &L[t][lA]);
    gload16(gA + t * 64 + 32, &L[t][lA + 8192]);
    gload16(gB + t * 64,      &L[t][lB]);
    gload16(gB + t * 64 + 32, &L[t][lB + 8192]);
  }

  const signed char* gAs = gA + 192;   // staging ptr -> tile 3
  const signed char* gBs = gB + 192;

  for (int it = 0; it < nk / 4 - 1; ++it) {
    TILE_BODY(0, 8, true, ACC_16(acc))
    TILE_BODY(1, 8, true, ACC_16(acc))
    TILE_BODY(2, 8, true, ACC_16(acc))
    TILE_BODY(3, 8, true, ACC_16(acc))
    gAs += 256; gBs += 256;
  }
  TILE_BODY(0, 8, true,  ACC_16(acc))   // t=nk-4, stages nk-1
  TILE_BODY(1, 8, false, ACC_16(acc))
  TILE_BODY(2, 4, false, ACC_16(acc))
  TILE_BODY(3, 0, false, ACC_16(acc))

  // epilogue: dequant + silu*mul, write h, track max|h|
  // C layout (32x32): col(lane)=l31, row = (q&3) + 8*(q>>2) + 4*kgl
  const float xsc = __uint_as_float(scal[0]) * (1.0f / QMAXF);
  float hmax = 0.f;
  #pragma unroll
  for (int m = 0; m < 2; ++m) {
    const int rbase = brow + wr * 64 + m * 32 + 4 * kgl;
    #pragma unroll
    for (int p = 0; p < 2; ++p) {
      const int col = bcol + (wc * 2 + p) * 32 + l31;
      const float sg = sgu[col] * xsc;
      const float su = sgu[I_DIM + col] * xsc;
      #pragma unroll
      for (int q = 0; q < 16; ++q) {
        const int row = rbase + (q & 3) + 8 * (q >> 2);
        float g = (float)acc[m][2 * p][q] * sg;
        float u = (float)acc[m][2 * p + 1][q] * su;
        float hv = (g / (1.f + expf(-g))) * u;
        hmax = fmaxf(hmax, fabsf(hv));
        hbuf[(size_t)row * I_DIM + col] = hv;
      }
    }
  }
  #pragma unroll
  for (int off = 32; off; off >>= 1) hmax = fmaxf(hmax, __shfl_xor(hmax, off));
  if (lane == 0) atomicMax(scal + 1, __float_as_uint(hmax));
}

// ---------------- quantize h ----------------

__global__ void quant_h_kernel(const float4* __restrict__ h4, v4i* __restrict__ q4,
                               const unsigned* __restrict__ scal) {
  const float hs = __uint_as_float(scal[1]) * (1.0f / QMAXF);
  const long i = (long)blockIdx.x * blockDim.x + threadIdx.x;
  v4i o;
  #pragma unroll
  for (int j = 0; j < 4; ++j) {
    float4 v = h4[i * 4 + j];
    float a = fminf(fmaxf(rintf(v.x / hs), -QMAXF), QMAXF);
    float b = fminf(fmaxf(rintf(v.y / hs), -QMAXF), QMAXF);
    float c = fminf(fmaxf(rintf(v.z / hs), -QMAXF), QMAXF);
    float d = fminf(fmaxf(rintf(v.w / hs), -QMAXF), QMAXF);
    o[j] = packq(a, b, c, d);
  }
  q4[i] = o;
}

__global__ void hscale_out_kernel(const unsigned* __restrict__ scal, float* __restrict__ dst) {
  dst[0] = __uint_as_float(scal[1]) * (1.0f / QMAXF);
}

// ---------------- GEMM2: out = (qh @ wdn^T) * (h_scale * s_down) ----------------
// 256x256 tile, BK=64, same single-sync unrolled ring as gemm1. Grid 256 = 1 block/CU.

__global__ __launch_bounds__(512, 2)
void gemm2_kernel(const signed char* __restrict__ qh,
                  const signed char* __restrict__ w8,
                  const float* __restrict__ sdn,
                  const unsigned* __restrict__ scal,
                  float* __restrict__ out)
{
  __shared__ signed char L[4][32768];

  const int tid  = threadIdx.x;
  const int lane = tid & 63;
  const int wid  = tid >> 6;
  const int wr   = wid >> 1;       // 0..3
  const int wc   = wid & 1;        // 0..1
  const int l31  = lane & 31;
  const int kgl  = lane >> 5;

  const int lin = blockIdx.x;                  // 256 = 8*32
  const int sw  = (lin & 7) * 32 + (lin >> 3);
  const int brow = (sw & 15) * 256;
  const int bcol = (sw >> 4) * 256;

  const int sr = tid & 255, sk = tid >> 8;
  const signed char* gA = qh + (size_t)(brow + sr) * I_DIM + sk * 16;
  const signed char* gB = w8 + (size_t)(bcol + sr) * I_DIM + sk * 16;
  const int lA = tid * 16;
  const int lB = 16384 + tid * 16;

  const int ab = (wr * 64 + l31) * 16;
  const int bb = 16384 + (wc * 128 + l31) * 16;

  v16i zero = {0};
  v16i acc[2][4];
  #pragma unroll
  for (int m = 0; m < 2; ++m)
    #pragma unroll
    for (int n = 0; n < 4; ++n) acc[m][n] = zero;

  const int nk = I_DIM / 64;  // 172 = 4*43
  #pragma unroll
  for (int t = 0; t < 3; ++t) {
    gload16(gA + t * 64,      &L[t][lA]);
    gload16(gA + t * 64 + 32, &L[t][lA + 8192]);
    gload16(gB + t * 64,      &L[t][lB]);
    gload16(gB + t * 64 + 32, &L[t][lB + 8192]);
  }

  const signed char* gAs = gA + 192;
  const signed char* gBs = gB + 192;

  for (int it = 0; it < nk / 4 - 1; ++it) {
    TILE_BODY(0, 8, true, ACC_16(acc))
    TILE_BODY(1, 8, true, ACC_16(acc))
    TILE_BODY(2, 8, true, ACC_16(acc))
    TILE_BODY(3, 8, true, ACC_16(acc))
    gAs += 256; gBs += 256;
  }
  TILE_BODY(0, 8, true,  ACC_16(acc))
  TILE_BODY(1, 8, false, ACC_16(acc))
  TILE_BODY(2, 4, false, ACC_16(acc))
  TILE_BODY(3, 0, false, ACC_16(acc))

  const float hsc = __uint_as_float(scal[1]) * (1.0f / QMAXF);
  #pragma unroll
  for (int m = 0; m < 2; ++m) {
    const int rbase = brow + wr * 64 + m * 32 + 4 * kgl;
    #pragma unroll
    for (int n = 0; n < 4; ++n) {
      const int col = bcol + wc * 128 + n * 32 + l31;
      const float s = sdn[col] * hsc;
      #pragma unroll
      for (int q = 0; q < 16; ++q) {
        const int row = rbase + (q & 3) + 8 * (q >> 2);
        out[(size_t)row * K1 + col] = (float)acc[m][n][q] * s;
      }
    }
  }
}

// ---------------- launch ----------------

extern "C" void kernel_launch(void* const* d_in, const int* in_sizes, int n_in,
                              void* d_out, int out_size, void* d_ws, size_t ws_size,
                              hipStream_t stream) {
  (void)in_sizes; (void)n_in; (void)out_size; (void)ws_size;
  const float* x   = (const float*)d_in[0];
  const float* wgu = (const float*)d_in[1];
  const float* sgu = (const float*)d_in[2];
  const float* wdn = (const float*)d_in[3];
  const float* sdn = (const float*)d_in[4];
  float* out = (float*)d_out;
  char* ws = (char*)d_ws;

  // ws layout (16B aligned): total ~360 MB
  signed char* qx  = (signed char*)(ws + 0LL);           // 16,777,216
  signed char* w8g = (signed char*)(ws + 16777216LL);    // 90,177,536
  signed char* w8d = (signed char*)(ws + 106954752LL);   // 45,088,768
  signed char* qh  = (signed char*)(ws + 152043520LL);   // 45,088,768
  float*       hb  = (float*)      (ws + 197132288LL);   // 180,355,072
  unsigned*    scal= (unsigned*)   (ws + 377487360LL);   // 256

  hipMemsetAsync(scal, 0, 256, stream);
  absmax_x_kernel<<<2048, 256, 0, stream>>>((const float4*)x, scal, T_DIM * K1 / 4);
  quant_x_kernel<<<4096, 256, 0, stream>>>((const float4*)x, (v4i*)qx, scal);
  conv_w_kernel<<<22016, 256, 0, stream>>>((const float4*)wgu, (v4i*)w8g);
  conv_w_kernel<<<11008, 256, 0, stream>>>((const float4*)wdn, (v4i*)w8d);

  gemm1_silu_kernel<<<1376, 512, 0, stream>>>(qx, w8g, sgu, scal, hb);

  quant_h_kernel<<<11008, 256, 0, stream>>>((const float4*)hb, (v4i*)qh, scal);
  hscale_out_kernel<<<1, 1, 0, stream>>>(scal, out + (size_t)T_DIM * K1);

  gemm2_kernel<<<256, 512, 0, stream>>>(qh, w8d, sdn, scal, out);
}

// Round 7
// 1186.501 us; speedup vs baseline: 1.0784x; 1.0784x over previous
//
#include <hip/hip_runtime.h>

#define T_DIM 4096
#define K1    4096      // H (hidden)
#define I_DIM 11008
#define QMAXF 127.0f

typedef int v4i  __attribute__((ext_vector_type(4)));

// ---------------- helpers ----------------

__device__ __forceinline__ void gload16(const void* g, void* l) {
  __builtin_amdgcn_global_load_lds((__attribute__((address_space(1))) unsigned int*)(g),
                                   (__attribute__((address_space(3))) unsigned int*)(l),
                                   16, 0, 0);
}

__device__ __forceinline__ int packq(float a, float b, float c, float d) {
  return ((int)a & 255) | (((int)b & 255) << 8) | (((int)c & 255) << 16) | (((int)d & 255) << 24);
}

#define MFMA(A, B, C) __builtin_amdgcn_mfma_i32_16x16x64_i8(A, B, C, 0, 0, 0)

// ---------------- pass 1: absmax(x) ----------------

__global__ void absmax_x_kernel(const float4* __restrict__ x4, unsigned* __restrict__ maxbits, int n4) {
  int tid = blockIdx.x * blockDim.x + threadIdx.x;
  int stride = gridDim.x * blockDim.x;
  float m = 0.f;
  for (int i = tid; i < n4; i += stride) {
    float4 v = x4[i];
    m = fmaxf(m, fmaxf(fmaxf(fabsf(v.x), fabsf(v.y)), fmaxf(fabsf(v.z), fabsf(v.w))));
  }
  #pragma unroll
  for (int off = 32; off; off >>= 1) m = fmaxf(m, __shfl_xor(m, off));
  if ((threadIdx.x & 63) == 0) atomicMax(maxbits, __float_as_uint(m));
}

// ---------------- pass 2: quantize x ----------------

__global__ void quant_x_kernel(const float4* __restrict__ x4, v4i* __restrict__ q4,
                               const unsigned* __restrict__ scal) {
  const float sx = __uint_as_float(scal[0]) * (1.0f / QMAXF);
  const long i = (long)blockIdx.x * blockDim.x + threadIdx.x;  // 16 floats per thread
  v4i o;
  #pragma unroll
  for (int j = 0; j < 4; ++j) {
    float4 v = x4[i * 4 + j];
    float a = fminf(fmaxf(rintf(v.x / sx), -QMAXF), QMAXF);
    float b = fminf(fmaxf(rintf(v.y / sx), -QMAXF), QMAXF);
    float c = fminf(fmaxf(rintf(v.z / sx), -QMAXF), QMAXF);
    float d = fminf(fmaxf(rintf(v.w / sx), -QMAXF), QMAXF);
    o[j] = packq(a, b, c, d);
  }
  q4[i] = o;
}

// ---------------- weight f32(int-valued) -> int8 ----------------

__global__ void conv_w_kernel(const float4* __restrict__ w4, v4i* __restrict__ q4) {
  const long i = (long)blockIdx.x * blockDim.x + threadIdx.x;  // 16 floats per thread
  v4i o;
  #pragma unroll
  for (int j = 0; j < 4; ++j) {
    float4 v = w4[i * 4 + j];
    o[j] = packq(rintf(v.x), rintf(v.y), rintf(v.z), rintf(v.w));
  }
  q4[i] = o;
}

// ================= m201-discipline phase machinery =================
// LDS per buffer: A [0,16384) layout [kslot:4][row:256][16B]; B [16384,32768) same.
// Fragment (16x16x64 i8): lane l holds row (l&15), kslot (l>>4) -> 1 ds_read_b128.
// Phase = { ds_reads; 2 gloads (half-stage); barrier; lgkm0; sched_barrier;
//           setprio(1); 16 MFMA; setprio(0); [vmcnt]; barrier }.
// vmcnt(4) only at phases 1,3 of each 2-tile iter (one tile of loads in flight).

#define STG_A(PTR, SB) { gload16((PTR), &L[SB][lA]); gload16((PTR) + 32, &L[SB][lA + 8192]); }
#define STG_B(PTR, SB) { gload16((PTR), &L[SB][lB]); gload16((PTR) + 32, &L[SB][lB + 8192]); }

#define PH0(CB, SB, APTR, DOST)                                              \
  {                                                                          \
    a0 = *(const v4i*)&L[CB][aoff];                                          \
    a1 = *(const v4i*)&L[CB][aoff + 256];                                    \
    a2 = *(const v4i*)&L[CB][aoff + 512];                                    \
    a3 = *(const v4i*)&L[CB][aoff + 768];                                    \
    b0 = *(const v4i*)&L[CB][boff];                                          \
    b1 = *(const v4i*)&L[CB][boff + 256];                                    \
    b2 = *(const v4i*)&L[CB][boff + 512];                                    \
    b3 = *(const v4i*)&L[CB][boff + 768];                                    \
    if (DOST) STG_A(APTR, SB);                                               \
    __builtin_amdgcn_s_barrier();                                            \
    asm volatile("s_waitcnt lgkmcnt(0)" ::: "memory");                       \
    __builtin_amdgcn_sched_barrier(0);                                       \
    __builtin_amdgcn_s_setprio(1);                                           \
    acc[0][0]=MFMA(a0,b0,acc[0][0]); acc[0][1]=MFMA(a0,b1,acc[0][1]);        \
    acc[0][2]=MFMA(a0,b2,acc[0][2]); acc[0][3]=MFMA(a0,b3,acc[0][3]);        \
    acc[1][0]=MFMA(a1,b0,acc[1][0]); acc[1][1]=MFMA(a1,b1,acc[1][1]);        \
    acc[1][2]=MFMA(a1,b2,acc[1][2]); acc[1][3]=MFMA(a1,b3,acc[1][3]);        \
    acc[2][0]=MFMA(a2,b0,acc[2][0]); acc[2][1]=MFMA(a2,b1,acc[2][1]);        \
    acc[2][2]=MFMA(a2,b2,acc[2][2]); acc[2][3]=MFMA(a2,b3,acc[2][3]);        \
    acc[3][0]=MFMA(a3,b0,acc[3][0]); acc[3][1]=MFMA(a3,b1,acc[3][1]);        \
    acc[3][2]=MFMA(a3,b2,acc[3][2]); acc[3][3]=MFMA(a3,b3,acc[3][3]);        \
    __builtin_amdgcn_s_setprio(0);                                           \
    __builtin_amdgcn_s_barrier();                                            \
    asm volatile("" ::: "memory");                                           \
  }

#define PH1(CB, SB, BPTR, DOST, VM)                                          \
  {                                                                          \
    a0 = *(const v4i*)&L[CB][aoff + 1024];                                   \
    a1 = *(const v4i*)&L[CB][aoff + 1280];                                   \
    a2 = *(const v4i*)&L[CB][aoff + 1536];                                   \
    a3 = *(const v4i*)&L[CB][aoff + 1792];                                   \
    if (DOST) STG_B(BPTR, SB);                                               \
    __builtin_amdgcn_s_barrier();                                            \
    asm volatile("s_waitcnt lgkmcnt(0)" ::: "memory");                       \
    __builtin_amdgcn_sched_barrier(0);                                       \
    __builtin_amdgcn_s_setprio(1);                                           \
    acc[4][0]=MFMA(a0,b0,acc[4][0]); acc[4][1]=MFMA(a0,b1,acc[4][1]);        \
    acc[4][2]=MFMA(a0,b2,acc[4][2]); acc[4][3]=MFMA(a0,b3,acc[4][3]);        \
    acc[5][0]=MFMA(a1,b0,acc[5][0]); acc[5][1]=MFMA(a1,b1,acc[5][1]);        \
    acc[5][2]=MFMA(a1,b2,acc[5][2]); acc[5][3]=MFMA(a1,b3,acc[5][3]);        \
    acc[6][0]=MFMA(a2,b0,acc[6][0]); acc[6][1]=MFMA(a2,b1,acc[6][1]);        \
    acc[6][2]=MFMA(a2,b2,acc[6][2]); acc[6][3]=MFMA(a2,b3,acc[6][3]);        \
    acc[7][0]=MFMA(a3,b0,acc[7][0]); acc[7][1]=MFMA(a3,b1,acc[7][1]);        \
    acc[7][2]=MFMA(a3,b2,acc[7][2]); acc[7][3]=MFMA(a3,b3,acc[7][3]);        \
    __builtin_amdgcn_s_setprio(0);                                           \
    asm volatile("s_waitcnt vmcnt(" VM ")" ::: "memory");                    \
    __builtin_amdgcn_s_barrier();                                            \
    asm volatile("" ::: "memory");                                           \
  }

// ---------------- GEMM1 fused: int8 GEMM + dequant + silu*mul + h absmax ----------------
// BM=256 T-rows x 256 staged B-rows (=128 h-cols, gate/up interleaved per 64-row group).
// 8 waves: wr in {0,1} (128-row half), wc in 0..3 (64 staged cols). Per-wave 128x64, acc[8][4].

__global__ __launch_bounds__(512, 2)
void gemm1_silu_kernel(const signed char* __restrict__ qx,
                       const signed char* __restrict__ w8,
                       const float* __restrict__ sgu,
                       unsigned* __restrict__ scal,
                       float* __restrict__ hbuf)
{
  __shared__ signed char L[4][32768];

  const int tid  = threadIdx.x;
  const int lane = tid & 63;
  const int wid  = tid >> 6;
  const int wr   = wid >> 2;       // 0..1
  const int wc   = wid & 3;        // 0..3
  const int ln15 = lane & 15;
  const int kq   = lane >> 4;      // 0..3

  const int lin = blockIdx.x;                  // 1376 = 8*172
  const int sw  = (lin & 7) * 172 + (lin >> 3);
  const int brow = (sw & 15) * 256;
  const int bcol = (sw >> 4) * 128;            // h-col base

  // staging: thread t, round r: staged row t&255, kslot r*2 + (t>>8)
  const int sro = tid & 255, skq = tid >> 8;
  const signed char* gA = qx + (size_t)(brow + sro) * K1 + skq * 16;
  const int grp = sro >> 6, w = sro & 63;
  const int gcolw = bcol + grp * 32 + (w & 31);
  const size_t srcrow = (w < 32) ? (size_t)gcolw : (size_t)(I_DIM + gcolw);
  const signed char* gB = w8 + srcrow * K1 + skq * 16;
  const int lA = tid * 16;
  const int lB = 16384 + tid * 16;

  const int aoff = kq * 4096 + (wr * 128 + ln15) * 16;           // + m*256
  const int boff = 16384 + kq * 4096 + (wc * 64 + ln15) * 16;    // + n*256

  v4i acc[8][4];
  #pragma unroll
  for (int m = 0; m < 8; ++m)
    #pragma unroll
    for (int n = 0; n < 4; ++n) acc[m][n] = v4i{0, 0, 0, 0};
  v4i a0, a1, a2, a3, b0, b1, b2, b3;

  // prologue: stage tiles 0,1; ensure tile 0 resident
  STG_A(gA, 0); STG_B(gB, 0);
  STG_A(gA + 64, 1); STG_B(gB + 64, 1);
  asm volatile("s_waitcnt vmcnt(4)" ::: "memory");
  __builtin_amdgcn_s_barrier();
  asm volatile("" ::: "memory");

  const signed char* gAp = gA;
  const signed char* gBp = gB;
  // main: 15 pairs x 4 tiles = tiles 0..59, staging tiles 2..61
  for (int p = 0; p < 15; ++p) {
    PH0(0, 2, gAp + 128, 1) PH1(0, 2, gBp + 128, 1, "4")
    PH0(1, 3, gAp + 192, 1) PH1(1, 3, gBp + 192, 1, "4")
    PH0(2, 0, gAp + 256, 1) PH1(2, 0, gBp + 256, 1, "4")
    PH0(3, 1, gAp + 320, 1) PH1(3, 1, gBp + 320, 1, "4")
    gAp += 256; gBp += 256;
  }
  // tail: tiles 60..63, stage 62,63 then drain
  PH0(0, 2, gAp + 128, 1) PH1(0, 2, gBp + 128, 1, "4")
  PH0(1, 3, gAp + 192, 1) PH1(1, 3, gBp + 192, 1, "4")
  PH0(2, 0, gAp,       0) PH1(2, 0, gBp,       0, "0")
  PH0(3, 1, gAp,       0) PH1(3, 1, gBp,       0, "0")

  // epilogue: dequant + silu*mul, write h, track max|h|
  // C (16x16): col = lane&15, row = (lane>>4)*4 + q  [verified R1-R3]
  const float xsc = __uint_as_float(scal[0]) * (1.0f / QMAXF);
  float hmax = 0.f;
  #pragma unroll
  for (int m = 0; m < 8; ++m) {
    const int row0 = brow + wr * 128 + m * 16 + kq * 4;
    #pragma unroll
    for (int n = 0; n < 2; ++n) {
      const int col = bcol + wc * 32 + n * 16 + ln15;
      const float sg = sgu[col] * xsc;
      const float su = sgu[I_DIM + col] * xsc;
      #pragma unroll
      for (int q = 0; q < 4; ++q) {
        float g = (float)acc[m][n][q] * sg;
        float u = (float)acc[m][n + 2][q] * su;
        float hv = (g / (1.f + expf(-g))) * u;
        hmax = fmaxf(hmax, fabsf(hv));
        hbuf[(size_t)(row0 + q) * I_DIM + col] = hv;
      }
    }
  }
  #pragma unroll
  for (int off = 32; off; off >>= 1) hmax = fmaxf(hmax, __shfl_xor(hmax, off));
  if (lane == 0) atomicMax(scal + 1, __float_as_uint(hmax));
}

// ---------------- quantize h ----------------

__global__ void quant_h_kernel(const float4* __restrict__ h4, v4i* __restrict__ q4,
                               const unsigned* __restrict__ scal) {
  const float hs = __uint_as_float(scal[1]) * (1.0f / QMAXF);
  const long i = (long)blockIdx.x * blockDim.x + threadIdx.x;
  v4i o;
  #pragma unroll
  for (int j = 0; j < 4; ++j) {
    float4 v = h4[i * 4 + j];
    float a = fminf(fmaxf(rintf(v.x / hs), -QMAXF), QMAXF);
    float b = fminf(fmaxf(rintf(v.y / hs), -QMAXF), QMAXF);
    float c = fminf(fmaxf(rintf(v.z / hs), -QMAXF), QMAXF);
    float d = fminf(fmaxf(rintf(v.w / hs), -QMAXF), QMAXF);
    o[j] = packq(a, b, c, d);
  }
  q4[i] = o;
}

__global__ void hscale_out_kernel(const unsigned* __restrict__ scal, float* __restrict__ dst) {
  dst[0] = __uint_as_float(scal[1]) * (1.0f / QMAXF);
}

// ---------------- GEMM2: out = (qh @ wdn^T) * (h_scale * s_down) ----------------
// BM=256 x BN=256, same phase discipline. Grid 256 = 1 block/CU.

__global__ __launch_bounds__(512, 2)
void gemm2_kernel(const signed char* __restrict__ qh,
                  const signed char* __restrict__ w8,
                  const float* __restrict__ sdn,
                  const unsigned* __restrict__ scal,
                  float* __restrict__ out)
{
  __shared__ signed char L[4][32768];

  const int tid  = threadIdx.x;
  const int lane = tid & 63;
  const int wid  = tid >> 6;
  const int wr   = wid >> 2;       // 0..1
  const int wc   = wid & 3;        // 0..3
  const int ln15 = lane & 15;
  const int kq   = lane >> 4;

  const int lin = blockIdx.x;                  // 256 = 8*32
  const int sw  = (lin & 7) * 32 + (lin >> 3);
  const int brow = (sw & 15) * 256;
  const int bcol = (sw >> 4) * 256;

  const int sro = tid & 255, skq = tid >> 8;
  const signed char* gA = qh + (size_t)(brow + sro) * I_DIM + skq * 16;
  const signed char* gB = w8 + (size_t)(bcol + sro) * I_DIM + skq * 16;
  const int lA = tid * 16;
  const int lB = 16384 + tid * 16;

  const int aoff = kq * 4096 + (wr * 128 + ln15) * 16;
  const int boff = 16384 + kq * 4096 + (wc * 64 + ln15) * 16;

  v4i acc[8][4];
  #pragma unroll
  for (int m = 0; m < 8; ++m)
    #pragma unroll
    for (int n = 0; n < 4; ++n) acc[m][n] = v4i{0, 0, 0, 0};
  v4i a0, a1, a2, a3, b0, b1, b2, b3;

  STG_A(gA, 0); STG_B(gB, 0);
  STG_A(gA + 64, 1); STG_B(gB + 64, 1);
  asm volatile("s_waitcnt vmcnt(4)" ::: "memory");
  __builtin_amdgcn_s_barrier();
  asm volatile("" ::: "memory");

  const signed char* gAp = gA;
  const signed char* gBp = gB;
  // main: 42 pairs = tiles 0..167, staging 2..169  (nk = 172)
  for (int p = 0; p < 42; ++p) {
    PH0(0, 2, gAp + 128, 1) PH1(0, 2, gBp + 128, 1, "4")
    PH0(1, 3, gAp + 192, 1) PH1(1, 3, gBp + 192, 1, "4")
    PH0(2, 0, gAp + 256, 1) PH1(2, 0, gBp + 256, 1, "4")
    PH0(3, 1, gAp + 320, 1) PH1(3, 1, gBp + 320, 1, "4")
    gAp += 256; gBp += 256;
  }
  // tail: tiles 168..171, stage 170,171 then drain
  PH0(0, 2, gAp + 128, 1) PH1(0, 2, gBp + 128, 1, "4")
  PH0(1, 3, gAp + 192, 1) PH1(1, 3, gBp + 192, 1, "4")
  PH0(2, 0, gAp,       0) PH1(2, 0, gBp,       0, "0")
  PH0(3, 1, gAp,       0) PH1(3, 1, gBp,       0, "0")

  const float hsc = __uint_as_float(scal[1]) * (1.0f / QMAXF);
  #pragma unroll
  for (int m = 0; m < 8; ++m) {
    const int row0 = brow + wr * 128 + m * 16 + kq * 4;
    #pragma unroll
    for (int n = 0; n < 4; ++n) {
      const int col = bcol + wc * 64 + n * 16 + ln15;
      const float s = sdn[col] * hsc;
      #pragma unroll
      for (int q = 0; q < 4; ++q)
        out[(size_t)(row0 + q) * K1 + col] = (float)acc[m][n][q] * s;
    }
  }
}

// ---------------- launch ----------------

extern "C" void kernel_launch(void* const* d_in, const int* in_sizes, int n_in,
                              void* d_out, int out_size, void* d_ws, size_t ws_size,
                              hipStream_t stream) {
  (void)in_sizes; (void)n_in; (void)out_size; (void)ws_size;
  const float* x   = (const float*)d_in[0];
  const float* wgu = (const float*)d_in[1];
  const float* sgu = (const float*)d_in[2];
  const float* wdn = (const float*)d_in[3];
  const float* sdn = (const float*)d_in[4];
  float* out = (float*)d_out;
  char* ws = (char*)d_ws;

  // ws layout (16B aligned): total ~360 MB
  signed char* qx  = (signed char*)(ws + 0LL);           // 16,777,216
  signed char* w8g = (signed char*)(ws + 16777216LL);    // 90,177,536
  signed char* w8d = (signed char*)(ws + 106954752LL);   // 45,088,768
  signed char* qh  = (signed char*)(ws + 152043520LL);   // 45,088,768
  float*       hb  = (float*)      (ws + 197132288LL);   // 180,355,072
  unsigned*    scal= (unsigned*)   (ws + 377487360LL);   // 256

  hipMemsetAsync(scal, 0, 256, stream);
  absmax_x_kernel<<<2048, 256, 0, stream>>>((const float4*)x, scal, T_DIM * K1 / 4);
  quant_x_kernel<<<4096, 256, 0, stream>>>((const float4*)x, (v4i*)qx, scal);
  conv_w_kernel<<<22016, 256, 0, stream>>>((const float4*)wgu, (v4i*)w8g);
  conv_w_kernel<<<11008, 256, 0, stream>>>((const float4*)wdn, (v4i*)w8d);

  gemm1_silu_kernel<<<1376, 512, 0, stream>>>(qx, w8g, sgu, scal, hb);

  quant_h_kernel<<<11008, 256, 0, stream>>>((const float4*)hb, (v4i*)qh, scal);
  hscale_out_kernel<<<1, 1, 0, stream>>>(scal, out + (size_t)T_DIM * K1);

  gemm2_kernel<<<256, 512, 0, stream>>>(qh, w8d, sdn, scal, out);
}